// Round 1
// baseline (680.653 us; speedup 1.0000x reference)
//
#include <hip/hip_runtime.h>
#include <math.h>

#define M_DIM 1024
#define N_DIM 1024
#define R_DIM 32

static __device__ __constant__ float C_HUB = 1.345f;

// ---------------------------------------------------------------------------
// Transpose X (1024x1024) -> XT
// ---------------------------------------------------------------------------
__global__ void transpose_x_kernel(const float* __restrict__ X, float* __restrict__ XT) {
    __shared__ float tile[32][33];
    int bx = blockIdx.x, by = blockIdx.y;
    int x = bx * 32 + threadIdx.x;
    int ybase = by * 32;
    for (int dy = threadIdx.y; dy < 32; dy += 8)
        tile[dy][threadIdx.x] = X[(ybase + dy) * N_DIM + x];
    __syncthreads();
    int xo = by * 32 + threadIdx.x;   // output column = original row
    int yob = bx * 32;                // output row base = original col
    for (int dy = threadIdx.y; dy < 32; dy += 8)
        XT[(yob + dy) * M_DIM + xo] = tile[threadIdx.x][dy];
}

// ---------------------------------------------------------------------------
// Transpose U (1024x32) -> UT (32x1024)
// ---------------------------------------------------------------------------
__global__ void transpose_u_kernel(const float* __restrict__ U, float* __restrict__ UT) {
    int id = blockIdx.x * 256 + threadIdx.x;   // 0..32767
    int c = id >> 10, m = id & 1023;
    UT[id] = U[m * R_DIM + c];
}

// ---------------------------------------------------------------------------
// Given AT (32x1024 row-major), compute W = (AT*ATt)^-1 * AT  (32x1024).
// For AT=UT this is pinv(U); for AT=V_new this is pinv(V_new)^T.
// Single block, 1024 threads. Gauss-Jordan in f64 (SPD, well-conditioned).
// ---------------------------------------------------------------------------
__global__ __launch_bounds__(1024) void pinv32_kernel(const float* __restrict__ AT,
                                                      float* __restrict__ Wout) {
    __shared__ float sG[32][32];
    __shared__ double sAug[32][64];
    __shared__ double sF[32];
    int tid = threadIdx.x;
    int c1 = tid >> 5, c2 = tid & 31;

    // G = AT * AT^T  (32x32), one thread per entry
    {
        const float4* r1 = (const float4*)(AT + (c1 << 10));
        const float4* r2 = (const float4*)(AT + (c2 << 10));
        float g = 0.f;
        for (int k = 0; k < 256; ++k) {
            float4 a = r1[k], b = r2[k];
            g += a.x * b.x + a.y * b.y + a.z * b.z + a.w * b.w;
        }
        sG[c1][c2] = g;
    }
    __syncthreads();

    // Augmented [G | I] in f64
    for (int idx = tid; idx < 2048; idx += 1024) {
        int r = idx >> 6, c = idx & 63;
        sAug[r][c] = (c < 32) ? (double)sG[r][c] : ((c - 32 == r) ? 1.0 : 0.0);
    }
    __syncthreads();

    // Gauss-Jordan, no pivoting (SPD)
    for (int k = 0; k < 32; ++k) {
        double pivinv = 1.0 / sAug[k][k];   // uniform read before any write
        __syncthreads();
        if (tid < 64) sAug[k][tid] *= pivinv;
        if (tid >= 64 && tid < 96) {
            int r = tid - 64;
            sF[r] = (r == k) ? 0.0 : sAug[r][k];
        }
        __syncthreads();
        for (int idx = tid; idx < 2048; idx += 1024) {
            int r = idx >> 6, c = idx & 63;
            if (r != k) sAug[r][c] -= sF[r] * sAug[k][c];
        }
        __syncthreads();
    }

    // Wout[c][m] = sum_c2 Ginv[c][c2] * AT[c2][m]; one thread per m
    int m = tid;
    float av[32];
    #pragma unroll
    for (int c22 = 0; c22 < 32; ++c22) av[c22] = AT[(c22 << 10) + m];
    #pragma unroll 4
    for (int c = 0; c < 32; ++c) {
        float acc = 0.f;
        #pragma unroll
        for (int c22 = 0; c22 < 32; ++c22)
            acc += (float)sAug[c][32 + c22] * av[c22];
        Wout[(c << 10) + m] = acc;
    }
}

// ---------------------------------------------------------------------------
// IRLS: one block (256 threads) per task (column j of X for phase 0,
// row i of X for phase 1).
//   Yr   : per-task contiguous y rows (XT for phase 0, X for phase 1)
//   A32  : 32x1024 row-major A^T       (UT for phase 0, V_new for phase 1)
//   W32  : 32x1024 row-major pinv form (Up for phase 0, VpT for phase 1)
//   kb   : 3x3 kernels base (conv_kernels for phase 0, +1023*9 for phase 1)
//   bsrc : initial beta source (V for phase 0 [strided], U for phase 1 [rows])
// ---------------------------------------------------------------------------
__global__ __launch_bounds__(256) void irls_kernel(
    const float* __restrict__ Yr, const float* __restrict__ A32,
    const float* __restrict__ W32, const float* __restrict__ kb,
    const float* __restrict__ bsrc, float* __restrict__ vnew,
    float* __restrict__ out, int phase)
{
    const int j = blockIdx.x;
    const int tid = threadIdx.x;
    const int lane = tid & 63, wave = tid >> 6;

    __shared__ __align__(16) float s_sort[1024];
    __shared__ float s_rpg[1026];     // guarded r_pseu: s_rpg[1+m], guards at 0,1025
    __shared__ float s_beta[R_DIM];
    __shared__ float s_S[3][34];      // guarded S: s_S[q][1+c'], guards at 0,33
    __shared__ float s_kern[9];
    __shared__ float s_part[4];

    if (tid < R_DIM)
        s_beta[tid] = (phase == 0) ? bsrc[tid * N_DIM + j] : bsrc[j * R_DIM + tid];
    if (tid >= 64 && tid < 64 + 9) {
        int t = tid - 64, p = t / 3, q = t % 3;
        // phase 0: kern[p][q] = kv[j][p][q]; phase 1: kern[p][q] = ku[j][q][p]
        s_kern[t] = (phase == 0) ? kb[j * 9 + t] : kb[j * 9 + q * 3 + p];
    }
    if (tid == 128) { s_rpg[0] = 0.f; s_rpg[1025] = 0.f; }
    if (tid >= 192 && tid < 195) { int q = tid - 192; s_S[q][0] = 0.f; s_S[q][33] = 0.f; }

    const float4 yv = ((const float4*)(Yr + (j << 10)))[tid];
    __syncthreads();

    // r = y - A @ beta, thread owns m = 4*tid .. 4*tid+3
    auto matvec = [&]() -> float4 {
        float4 acc = yv;
        #pragma unroll 4
        for (int c = 0; c < R_DIM; ++c) {
            float b = s_beta[c];
            float4 a = ((const float4*)(A32 + (c << 10)))[tid];
            acc.x -= a.x * b; acc.y -= a.y * b; acc.z -= a.z * b; acc.w -= a.w * b;
        }
        return acc;
    };

    // full bitonic sort of s_sort[0..1023] ascending; returns median
    auto bitonic_med = [&]() -> float {
        for (int k = 2; k <= 1024; k <<= 1) {
            for (int jj = k >> 1; jj > 0; jj >>= 1) {
                __syncthreads();
                #pragma unroll
                for (int ii = 0; ii < 4; ++ii) {
                    int i = tid + (ii << 8);
                    int l = i ^ jj;
                    if (l > i) {
                        float a = s_sort[i], b = s_sort[l];
                        bool asc = ((i & k) == 0);
                        if ((a > b) == asc) { s_sort[i] = b; s_sort[l] = a; }
                    }
                }
            }
        }
        __syncthreads();
        float med = 0.5f * (s_sort[511] + s_sort[512]);
        __syncthreads();
        return med;
    };

    auto block_sum = [&](float v) -> float {
        #pragma unroll
        for (int off = 32; off > 0; off >>= 1) v += __shfl_down(v, off, 64);
        if (lane == 0) s_part[wave] = v;
        __syncthreads();
        float r = s_part[0] + s_part[1] + s_part[2] + s_part[3];
        __syncthreads();
        return r;
    };

    // ---- initial scale from r0 ----
    float4 r0 = matvec();
    ((float4*)s_sort)[tid] = r0;
    float med = bitonic_med();
    float4 dv;
    dv.x = fabsf(r0.x - med); dv.y = fabsf(r0.y - med);
    dv.z = fabsf(r0.z - med); dv.w = fabsf(r0.w - med);
    ((float4*)s_sort)[tid] = dv;
    float mad = bitonic_med();
    float scale = 1.4815f * mad;

    const float denom = 2.0f * 0.7102f * (1024.0f - 32.0f - 1.0f);
    const float C2 = C_HUB * C_HUB;

    for (int it = 0; it < 3; ++it) {
        float4 r = matvec();

        // r_chi = psi(u)*u - rho(u) == 0.5*min(u^2, C^2)
        float u0 = r.x / scale, u1 = r.y / scale, u2 = r.z / scale, u3 = r.w / scale;
        float part = 0.5f * (fminf(u0 * u0, C2) + fminf(u1 * u1, C2) +
                             fminf(u2 * u2, C2) + fminf(u3 * u3, C2));
        float ssum = block_sum(part);
        scale = sqrtf(2.0f * scale * scale / denom * ssum);

        // r_pseu = clip(r/scale, -C, C) * scale
        float t0 = fminf(fmaxf(r.x / scale, -C_HUB), C_HUB) * scale;
        float t1 = fminf(fmaxf(r.y / scale, -C_HUB), C_HUB) * scale;
        float t2 = fminf(fmaxf(r.z / scale, -C_HUB), C_HUB) * scale;
        float t3 = fminf(fmaxf(r.w / scale, -C_HUB), C_HUB) * scale;
        int base = (tid << 2) + 1;
        s_rpg[base + 0] = t0; s_rpg[base + 1] = t1;
        s_rpg[base + 2] = t2; s_rpg[base + 3] = t3;
        __syncthreads();

        // S[q][c'] = sum_k W[c'][k] * rp[k+1-q]; each wave handles 8 c' rows
        #pragma unroll
        for (int cc = 0; cc < 8; ++cc) {
            int cp = (wave << 3) + cc;
            const float4* wrow = (const float4*)(W32 + (cp << 10));
            float p0 = 0.f, p1 = 0.f, p2 = 0.f;
            #pragma unroll
            for (int kk = 0; kk < 4; ++kk) {
                int k4 = lane + (kk << 6);
                float4 wv = wrow[k4];
                int kk0 = (k4 << 2);
                float r_0 = s_rpg[kk0 + 0], r_1 = s_rpg[kk0 + 1], r_2 = s_rpg[kk0 + 2];
                float r_3 = s_rpg[kk0 + 3], r_4 = s_rpg[kk0 + 4], r_5 = s_rpg[kk0 + 5];
                p2 += wv.x * r_0 + wv.y * r_1 + wv.z * r_2 + wv.w * r_3;  // q=2: rp[k-1]
                p1 += wv.x * r_1 + wv.y * r_2 + wv.z * r_3 + wv.w * r_4;  // q=1: rp[k]
                p0 += wv.x * r_2 + wv.y * r_3 + wv.z * r_4 + wv.w * r_5;  // q=0: rp[k+1]
            }
            #pragma unroll
            for (int off = 32; off > 0; off >>= 1) {
                p0 += __shfl_down(p0, off, 64);
                p1 += __shfl_down(p1, off, 64);
                p2 += __shfl_down(p2, off, 64);
            }
            if (lane == 0) { s_S[0][cp + 1] = p0; s_S[1][cp + 1] = p1; s_S[2][cp + 1] = p2; }
        }
        __syncthreads();

        // beta[c] += sum_{p,q} kern[p][q] * S[q][c+p-1]
        if (tid < R_DIM) {
            float d = 0.f;
            #pragma unroll
            for (int p = 0; p < 3; ++p)
                #pragma unroll
                for (int q = 0; q < 3; ++q)
                    d += s_kern[p * 3 + q] * s_S[q][tid + p];
            s_beta[tid] += d;
        }
        __syncthreads();
    }

    if (tid < R_DIM) {
        float b = s_beta[tid];
        if (phase == 0) {
            vnew[tid * N_DIM + j] = b;            // V_new for later phases
            out[tid * 2048 + 1024 + j] = b;       // right half of output
        } else {
            out[tid * 2048 + j] = b;              // U_new.T, left half
        }
    }
}

// ---------------------------------------------------------------------------
extern "C" void kernel_launch(void* const* d_in, const int* in_sizes, int n_in,
                              void* d_out, int out_size, void* d_ws, size_t ws_size,
                              hipStream_t stream) {
    const float* X  = (const float*)d_in[0];
    const float* U  = (const float*)d_in[1];
    const float* V  = (const float*)d_in[2];
    const float* CK = (const float*)d_in[3];
    float* out = (float*)d_out;

    float* f   = (float*)d_ws;
    float* XT  = f;                    // 1024*1024
    float* UT  = f + (1 << 20);        // 32*1024
    float* Up  = UT + 32768;           // 32*1024
    float* Vn  = Up + 32768;           // 32*1024
    float* VpT = Vn + 32768;           // 32*1024

    transpose_x_kernel<<<dim3(32, 32), dim3(32, 8), 0, stream>>>(X, XT);
    transpose_u_kernel<<<128, 256, 0, stream>>>(U, UT);
    pinv32_kernel<<<1, 1024, 0, stream>>>(UT, Up);
    irls_kernel<<<1024, 256, 0, stream>>>(XT, UT, Up, CK, V, Vn, out, 0);
    pinv32_kernel<<<1, 1024, 0, stream>>>(Vn, VpT);
    irls_kernel<<<1024, 256, 0, stream>>>(X, Vn, VpT, CK + 1023 * 9, U, nullptr, out, 1);
}

// Round 2
// 388.940 us; speedup vs baseline: 1.7500x; 1.7500x over previous
//
#include <hip/hip_runtime.h>
#include <math.h>

#define M_DIM 1024
#define N_DIM 1024
#define R_DIM 32

static __device__ __constant__ float C_HUB = 1.345f;

// ---------------------------------------------------------------------------
// Transpose X (1024x1024) -> XT
// ---------------------------------------------------------------------------
__global__ void transpose_x_kernel(const float* __restrict__ X, float* __restrict__ XT) {
    __shared__ float tile[32][33];
    int bx = blockIdx.x, by = blockIdx.y;
    int x = bx * 32 + threadIdx.x;
    int ybase = by * 32;
    for (int dy = threadIdx.y; dy < 32; dy += 8)
        tile[dy][threadIdx.x] = X[(ybase + dy) * N_DIM + x];
    __syncthreads();
    int xo = by * 32 + threadIdx.x;   // output column = original row
    int yob = bx * 32;                // output row base = original col
    for (int dy = threadIdx.y; dy < 32; dy += 8)
        XT[(yob + dy) * M_DIM + xo] = tile[threadIdx.x][dy];
}

// ---------------------------------------------------------------------------
// Transpose U (1024x32) -> UT (32x1024)
// ---------------------------------------------------------------------------
__global__ void transpose_u_kernel(const float* __restrict__ U, float* __restrict__ UT) {
    int id = blockIdx.x * 256 + threadIdx.x;   // 0..32767
    int c = id >> 10, m = id & 1023;
    UT[id] = U[m * R_DIM + c];
}

// ---------------------------------------------------------------------------
// Stage 1 of pinv: partial Gram. Block b computes G_b = AT[:,k0:k0+128] x
// AT[:,k0:k0+128]^T (32x32) into Gpart[b].
// ---------------------------------------------------------------------------
__global__ __launch_bounds__(256) void gram_kernel(const float* __restrict__ AT,
                                                   float* __restrict__ Gpart) {
    __shared__ float s[32][129];   // +1 pad: bank = (c*129+k)%32 = (c+k)%32
    const int b = blockIdx.x, tid = threadIdx.x;
    const int k0 = b << 7;
    for (int i = tid; i < 4096; i += 256) {
        int r = i >> 7, c = i & 127;
        s[r][c] = AT[(r << 10) + k0 + c];
    }
    __syncthreads();
    const int c2 = tid & 31, c1b = tid >> 5;
    float acc[4] = {0.f, 0.f, 0.f, 0.f};
    for (int k = 0; k < 128; ++k) {
        float bv = s[c2][k];
        #pragma unroll
        for (int i = 0; i < 4; ++i)
            acc[i] += s[c1b + (i << 3)][k] * bv;
    }
    #pragma unroll
    for (int i = 0; i < 4; ++i)
        Gpart[(b << 10) + ((c1b + (i << 3)) << 5) + c2] = acc[i];
}

// ---------------------------------------------------------------------------
// Stage 2 of pinv: sum the 8 partials into f64 G, invert 32x32 via
// Gauss-Jordan fully in registers on ONE wave (lane = column of [G | I]).
// No barriers, no LDS; pivot row/col broadcast via readlane-style __shfl.
// All loops fully unrolled so col[] stays in registers (rule #20).
// ---------------------------------------------------------------------------
__global__ __launch_bounds__(64) void inv_kernel(const float* __restrict__ Gpart,
                                                 float* __restrict__ Ginv) {
    const int lane = threadIdx.x;
    double col[32];
    if (lane < 32) {
        #pragma unroll
        for (int r = 0; r < 32; ++r) {
            double a = 0.0;
            #pragma unroll
            for (int b = 0; b < 8; ++b) a += (double)Gpart[(b << 10) + (r << 5) + lane];
            col[r] = a;
        }
    } else {
        #pragma unroll
        for (int r = 0; r < 32; ++r) col[r] = (lane - 32 == r) ? 1.0 : 0.0;
    }
    #pragma unroll
    for (int k = 0; k < 32; ++k) {
        double piv = __shfl(col[k], k, 64);
        double pinv_ = 1.0 / piv;
        col[k] *= pinv_;
        #pragma unroll
        for (int r = 0; r < 32; ++r) {
            if (r == k) continue;
            double f = __shfl(col[r], k, 64);
            col[r] -= f * col[k];
        }
    }
    if (lane >= 32) {
        #pragma unroll
        for (int r = 0; r < 32; ++r)
            Ginv[(r << 5) + (lane - 32)] = (float)col[r];
    }
}

// ---------------------------------------------------------------------------
// Stage 3 of pinv: W = Ginv (32x32) * AT (32x1024). Block handles 32 columns.
// ---------------------------------------------------------------------------
__global__ __launch_bounds__(256) void wout_kernel(const float* __restrict__ Ginv,
                                                   const float* __restrict__ AT,
                                                   float* __restrict__ W) {
    __shared__ float sg[1024];
    const int tid = threadIdx.x;
    #pragma unroll
    for (int i = 0; i < 4; ++i) sg[tid + (i << 8)] = Ginv[tid + (i << 8)];
    __syncthreads();
    const int ml = tid & 31, cg = tid >> 5;
    const int m = (blockIdx.x << 5) + ml;
    float av[32];
    #pragma unroll
    for (int c2 = 0; c2 < 32; ++c2) av[c2] = AT[(c2 << 10) + m];
    #pragma unroll
    for (int i = 0; i < 4; ++i) {
        int c = cg + (i << 3);
        float acc = 0.f;
        #pragma unroll
        for (int c2 = 0; c2 < 32; ++c2) acc += sg[(c << 5) + c2] * av[c2];
        W[(c << 10) + m] = acc;
    }
}

// ---------------------------------------------------------------------------
// IRLS: one block (256 threads) per task (column j of X for phase 0,
// row i of X for phase 1).
// ---------------------------------------------------------------------------
__global__ __launch_bounds__(256) void irls_kernel(
    const float* __restrict__ Yr, const float* __restrict__ A32,
    const float* __restrict__ W32, const float* __restrict__ kb,
    const float* __restrict__ bsrc, float* __restrict__ vnew,
    float* __restrict__ out, int phase)
{
    const int j = blockIdx.x;
    const int tid = threadIdx.x;
    const int lane = tid & 63, wave = tid >> 6;

    __shared__ __align__(16) float s_sort[1024];
    __shared__ float s_rpg[1026];     // guarded r_pseu: s_rpg[1+m], guards at 0,1025
    __shared__ float s_beta[R_DIM];
    __shared__ float s_S[3][34];      // guarded S: s_S[q][1+c'], guards at 0,33
    __shared__ float s_kern[9];
    __shared__ float s_part[4];

    if (tid < R_DIM)
        s_beta[tid] = (phase == 0) ? bsrc[tid * N_DIM + j] : bsrc[j * R_DIM + tid];
    if (tid >= 64 && tid < 64 + 9) {
        int t = tid - 64, p = t / 3, q = t % 3;
        // phase 0: kern[p][q] = kv[j][p][q]; phase 1: kern[p][q] = ku[j][q][p]
        s_kern[t] = (phase == 0) ? kb[j * 9 + t] : kb[j * 9 + q * 3 + p];
    }
    if (tid == 128) { s_rpg[0] = 0.f; s_rpg[1025] = 0.f; }
    if (tid >= 192 && tid < 195) { int q = tid - 192; s_S[q][0] = 0.f; s_S[q][33] = 0.f; }

    const float4 yv = ((const float4*)(Yr + (j << 10)))[tid];
    __syncthreads();

    // r = y - A @ beta, thread owns m = 4*tid .. 4*tid+3
    auto matvec = [&]() -> float4 {
        float4 acc = yv;
        #pragma unroll 4
        for (int c = 0; c < R_DIM; ++c) {
            float b = s_beta[c];
            float4 a = ((const float4*)(A32 + (c << 10)))[tid];
            acc.x -= a.x * b; acc.y -= a.y * b; acc.z -= a.z * b; acc.w -= a.w * b;
        }
        return acc;
    };

    // full bitonic sort of s_sort[0..1023] ascending; returns median
    auto bitonic_med = [&]() -> float {
        for (int k = 2; k <= 1024; k <<= 1) {
            for (int jj = k >> 1; jj > 0; jj >>= 1) {
                __syncthreads();
                #pragma unroll
                for (int ii = 0; ii < 4; ++ii) {
                    int i = tid + (ii << 8);
                    int l = i ^ jj;
                    if (l > i) {
                        float a = s_sort[i], b = s_sort[l];
                        bool asc = ((i & k) == 0);
                        if ((a > b) == asc) { s_sort[i] = b; s_sort[l] = a; }
                    }
                }
            }
        }
        __syncthreads();
        float med = 0.5f * (s_sort[511] + s_sort[512]);
        __syncthreads();
        return med;
    };

    auto block_sum = [&](float v) -> float {
        #pragma unroll
        for (int off = 32; off > 0; off >>= 1) v += __shfl_down(v, off, 64);
        if (lane == 0) s_part[wave] = v;
        __syncthreads();
        float r = s_part[0] + s_part[1] + s_part[2] + s_part[3];
        __syncthreads();
        return r;
    };

    // ---- initial scale from r0 ----
    float4 r0 = matvec();
    ((float4*)s_sort)[tid] = r0;
    float med = bitonic_med();
    float4 dv;
    dv.x = fabsf(r0.x - med); dv.y = fabsf(r0.y - med);
    dv.z = fabsf(r0.z - med); dv.w = fabsf(r0.w - med);
    ((float4*)s_sort)[tid] = dv;
    float mad = bitonic_med();
    float scale = 1.4815f * mad;

    const float denom = 2.0f * 0.7102f * (1024.0f - 32.0f - 1.0f);
    const float C2 = C_HUB * C_HUB;

    for (int it = 0; it < 3; ++it) {
        float4 r = matvec();

        // r_chi = psi(u)*u - rho(u) == 0.5*min(u^2, C^2)
        float u0 = r.x / scale, u1 = r.y / scale, u2 = r.z / scale, u3 = r.w / scale;
        float part = 0.5f * (fminf(u0 * u0, C2) + fminf(u1 * u1, C2) +
                             fminf(u2 * u2, C2) + fminf(u3 * u3, C2));
        float ssum = block_sum(part);
        scale = sqrtf(2.0f * scale * scale / denom * ssum);

        // r_pseu = clip(r/scale, -C, C) * scale
        float t0 = fminf(fmaxf(r.x / scale, -C_HUB), C_HUB) * scale;
        float t1 = fminf(fmaxf(r.y / scale, -C_HUB), C_HUB) * scale;
        float t2 = fminf(fmaxf(r.z / scale, -C_HUB), C_HUB) * scale;
        float t3 = fminf(fmaxf(r.w / scale, -C_HUB), C_HUB) * scale;
        int base = (tid << 2) + 1;
        s_rpg[base + 0] = t0; s_rpg[base + 1] = t1;
        s_rpg[base + 2] = t2; s_rpg[base + 3] = t3;
        __syncthreads();

        // S[q][c'] = sum_k W[c'][k] * rp[k+1-q]; each wave handles 8 c' rows
        #pragma unroll
        for (int cc = 0; cc < 8; ++cc) {
            int cp = (wave << 3) + cc;
            const float4* wrow = (const float4*)(W32 + (cp << 10));
            float p0 = 0.f, p1 = 0.f, p2 = 0.f;
            #pragma unroll
            for (int kk = 0; kk < 4; ++kk) {
                int k4 = lane + (kk << 6);
                float4 wv = wrow[k4];
                int kk0 = (k4 << 2);
                float r_0 = s_rpg[kk0 + 0], r_1 = s_rpg[kk0 + 1], r_2 = s_rpg[kk0 + 2];
                float r_3 = s_rpg[kk0 + 3], r_4 = s_rpg[kk0 + 4], r_5 = s_rpg[kk0 + 5];
                p2 += wv.x * r_0 + wv.y * r_1 + wv.z * r_2 + wv.w * r_3;  // q=2: rp[k-1]
                p1 += wv.x * r_1 + wv.y * r_2 + wv.z * r_3 + wv.w * r_4;  // q=1: rp[k]
                p0 += wv.x * r_2 + wv.y * r_3 + wv.z * r_4 + wv.w * r_5;  // q=0: rp[k+1]
            }
            #pragma unroll
            for (int off = 32; off > 0; off >>= 1) {
                p0 += __shfl_down(p0, off, 64);
                p1 += __shfl_down(p1, off, 64);
                p2 += __shfl_down(p2, off, 64);
            }
            if (lane == 0) { s_S[0][cp + 1] = p0; s_S[1][cp + 1] = p1; s_S[2][cp + 1] = p2; }
        }
        __syncthreads();

        // beta[c] += sum_{p,q} kern[p][q] * S[q][c+p-1]
        if (tid < R_DIM) {
            float d = 0.f;
            #pragma unroll
            for (int p = 0; p < 3; ++p)
                #pragma unroll
                for (int q = 0; q < 3; ++q)
                    d += s_kern[p * 3 + q] * s_S[q][tid + p];
            s_beta[tid] += d;
        }
        __syncthreads();
    }

    if (tid < R_DIM) {
        float b = s_beta[tid];
        if (phase == 0) {
            vnew[tid * N_DIM + j] = b;            // V_new for later phases
            out[tid * 2048 + 1024 + j] = b;       // right half of output
        } else {
            out[tid * 2048 + j] = b;              // U_new.T, left half
        }
    }
}

// ---------------------------------------------------------------------------
extern "C" void kernel_launch(void* const* d_in, const int* in_sizes, int n_in,
                              void* d_out, int out_size, void* d_ws, size_t ws_size,
                              hipStream_t stream) {
    const float* X  = (const float*)d_in[0];
    const float* U  = (const float*)d_in[1];
    const float* V  = (const float*)d_in[2];
    const float* CK = (const float*)d_in[3];
    float* out = (float*)d_out;

    float* f     = (float*)d_ws;
    float* XT    = f;                    // 1024*1024
    float* UT    = f + (1 << 20);        // 32*1024
    float* Up    = UT + 32768;           // 32*1024
    float* Vn    = Up + 32768;           // 32*1024
    float* VpT   = Vn + 32768;           // 32*1024
    float* Gpart = VpT + 32768;          // 8*1024
    float* Ginv  = Gpart + 8192;         // 1024

    transpose_x_kernel<<<dim3(32, 32), dim3(32, 8), 0, stream>>>(X, XT);
    transpose_u_kernel<<<128, 256, 0, stream>>>(U, UT);

    gram_kernel<<<8, 256, 0, stream>>>(UT, Gpart);
    inv_kernel<<<1, 64, 0, stream>>>(Gpart, Ginv);
    wout_kernel<<<32, 256, 0, stream>>>(Ginv, UT, Up);

    irls_kernel<<<1024, 256, 0, stream>>>(XT, UT, Up, CK, V, Vn, out, 0);

    gram_kernel<<<8, 256, 0, stream>>>(Vn, Gpart);
    inv_kernel<<<1, 64, 0, stream>>>(Gpart, Ginv);
    wout_kernel<<<32, 256, 0, stream>>>(Ginv, Vn, VpT);

    irls_kernel<<<1024, 256, 0, stream>>>(X, Vn, VpT, CK + 1023 * 9, U, nullptr, out, 1);
}

// Round 3
// 278.481 us; speedup vs baseline: 2.4442x; 1.3966x over previous
//
#include <hip/hip_runtime.h>
#include <math.h>

#define C_HUB 1.345f

// ---------------- DPP helpers (VALU-pipe cross-lane, canonical GCN idiom) ----
template<int CTRL, bool BC>
__device__ __forceinline__ float fdpp(float old_, float src) {
    return __int_as_float(__builtin_amdgcn_update_dpp(
        __float_as_int(old_), __float_as_int(src), CTRL, 0xf, 0xf, BC));
}
// wave64 sum; result valid at lane 63 only
__device__ __forceinline__ float wsum63(float v) {
    v += fdpp<0x111, true>(0.f, v);   // row_shr:1
    v += fdpp<0x112, true>(0.f, v);   // row_shr:2
    v += fdpp<0x114, true>(0.f, v);   // row_shr:4
    v += fdpp<0x118, true>(0.f, v);   // row_shr:8
    v += fdpp<0x142, true>(0.f, v);   // row_bcast:15
    v += fdpp<0x143, true>(0.f, v);   // row_bcast:31
    return v;
}
template<int CTRL>
__device__ __forceinline__ unsigned udpp_keep(unsigned v) {
    return (unsigned)__builtin_amdgcn_update_dpp((int)v, (int)v, CTRL, 0xf, 0xf, false);
}
// wave64 unsigned min; valid at lane 63
__device__ __forceinline__ unsigned wmin63(unsigned v) {
    v = min(v, udpp_keep<0x111>(v));
    v = min(v, udpp_keep<0x112>(v));
    v = min(v, udpp_keep<0x114>(v));
    v = min(v, udpp_keep<0x118>(v));
    v = min(v, udpp_keep<0x142>(v));
    v = min(v, udpp_keep<0x143>(v));
    return v;
}
__device__ __forceinline__ float bcast63(float v) {
    return __int_as_float(__builtin_amdgcn_readlane(__float_as_int(v), 63));
}

// monotone f32 <-> u32 key maps
__device__ __forceinline__ unsigned f2k(float f) {
    unsigned b = __float_as_uint(f);
    return (b & 0x80000000u) ? ~b : (b | 0x80000000u);
}
__device__ __forceinline__ float k2f(unsigned k) {
    return __uint_as_float((k & 0x80000000u) ? (k ^ 0x80000000u) : ~k);
}

// n-th smallest (1-indexed) of 1024 keys (16/lane), wave-synchronous
__device__ __forceinline__ unsigned wave_sel(const unsigned k[16], int n) {
    unsigned hi = 0u;
    for (int b = 31; b >= 0; --b) {
        unsigned pat = hi >> b;
        int cnt = 0;
        #pragma unroll
        for (int v = 0; v < 16; ++v)
            cnt += __popcll(__ballot((k[v] >> b) == pat));
        if (n > cnt) { hi |= (1u << b); n -= cnt; }
    }
    return hi;
}
// exact median (mean of middle two) of the 1024 keys
__device__ __forceinline__ float wave_median(const unsigned k[16]) {
    unsigned k1 = wave_sel(k, 512);
    int cle = 0;
    #pragma unroll
    for (int v = 0; v < 16; ++v) cle += __popcll(__ballot(k[v] <= k1));
    unsigned k2 = k1;
    if (cle < 513) {
        unsigned mg = 0xFFFFFFFFu;
        #pragma unroll
        for (int v = 0; v < 16; ++v) if (k[v] > k1) mg = min(mg, k[v]);
        mg = wmin63(mg);
        k2 = (unsigned)__builtin_amdgcn_readlane((int)mg, 63);
    }
    return 0.5f * (k2f(k1) + k2f(k2));
}

// ---------------------------------------------------------------------------
// Fused transpose: X (1024x1024)->XT plus U (1024x32)->UT (blocks with by==32)
// ---------------------------------------------------------------------------
__global__ void transpose_kernel(const float* __restrict__ X, float* __restrict__ XT,
                                 const float* __restrict__ U, float* __restrict__ UT) {
    if (blockIdx.y == 32) {
        int id = blockIdx.x * 256 + threadIdx.y * 32 + threadIdx.x;  // 0..8191
        #pragma unroll
        for (int s = 0; s < 4; ++s) {
            int e = id + s * 8192;
            int c = e >> 10, m = e & 1023;
            UT[e] = U[m * 32 + c];
        }
        return;
    }
    __shared__ float tile[32][33];
    int bx = blockIdx.x, by = blockIdx.y;
    int x = bx * 32 + threadIdx.x;
    int ybase = by * 32;
    for (int dy = threadIdx.y; dy < 32; dy += 8)
        tile[dy][threadIdx.x] = X[(ybase + dy) * 1024 + x];
    __syncthreads();
    int xo = by * 32 + threadIdx.x;
    int yob = bx * 32;
    for (int dy = threadIdx.y; dy < 32; dy += 8)
        XT[(yob + dy) * 1024 + xo] = tile[threadIdx.x][dy];
}

// ---------------------------------------------------------------------------
// Partial Gram: block b computes AT[:,128b:128b+128] * (same)^T into Gpart[b]
// ---------------------------------------------------------------------------
__global__ __launch_bounds__(256) void gram_kernel(const float* __restrict__ AT,
                                                   float* __restrict__ Gpart) {
    __shared__ float s[32][129];
    const int b = blockIdx.x, tid = threadIdx.x;
    const int k0 = b << 7;
    for (int i = tid; i < 4096; i += 256) {
        int r = i >> 7, c = i & 127;
        s[r][c] = AT[(r << 10) + k0 + c];
    }
    __syncthreads();
    const int c2 = tid & 31, c1b = tid >> 5;
    float acc[4] = {0.f, 0.f, 0.f, 0.f};
    for (int k = 0; k < 128; ++k) {
        float bv = s[c2][k];
        #pragma unroll
        for (int i = 0; i < 4; ++i)
            acc[i] += s[c1b + (i << 3)][k] * bv;
    }
    #pragma unroll
    for (int i = 0; i < 4; ++i)
        Gpart[(b << 10) + ((c1b + (i << 3)) << 5) + c2] = acc[i];
}

// ---------------------------------------------------------------------------
// Sum partials, invert 32x32 SPD Gram via f32 Gauss-Jordan on one wave.
// ---------------------------------------------------------------------------
__global__ __launch_bounds__(64) void inv_kernel(const float* __restrict__ Gpart,
                                                 float* __restrict__ Ginv) {
    const int lane = threadIdx.x;
    float col[32];
    if (lane < 32) {
        #pragma unroll
        for (int r = 0; r < 32; ++r) {
            float a = 0.f;
            #pragma unroll
            for (int b = 0; b < 8; ++b) a += Gpart[(b << 10) + (r << 5) + lane];
            col[r] = a;
        }
    } else {
        #pragma unroll
        for (int r = 0; r < 32; ++r) col[r] = (lane - 32 == r) ? 1.f : 0.f;
    }
    #pragma unroll
    for (int k = 0; k < 32; ++k) {
        float piv = __shfl(col[k], k, 64);
        float pr = 1.0f / piv;
        col[k] *= pr;
        #pragma unroll
        for (int r = 0; r < 32; ++r) {
            if (r == k) continue;
            float f = __shfl(col[r], k, 64);
            col[r] -= f * col[k];
        }
    }
    if (lane >= 32) {
        #pragma unroll
        for (int r = 0; r < 32; ++r)
            Ginv[(r << 5) + (lane - 32)] = col[r];
    }
}

// ---------------------------------------------------------------------------
// IRLS: 4 tasks per block (tasks j = 4*blockIdx.x + t), 256 threads.
// Thread i owns elements 4i..4i+3 of every task. Wave w owns task w's medians.
// Uses z[q] = A * shifted-rp and folds Ginv into the beta update (W never formed).
// ---------------------------------------------------------------------------
__global__ __launch_bounds__(256) void irls_kernel(
    const float* __restrict__ Yr, const float* __restrict__ A32,
    const float* __restrict__ Ginv, const float* __restrict__ kb,
    const float* __restrict__ bsrc, float* __restrict__ vnew,
    float* __restrict__ out, int phase)
{
    const int b4 = blockIdx.x;
    const int tid = threadIdx.x;
    const int lane = tid & 63, wv_id = tid >> 6;

    __shared__ __align__(16) float s_rp[4][1024];
    __shared__ __align__(16) float s_beta4[32][4];      // [c][t]
    __shared__ __align__(16) float s_ginvP[34 * 32];    // row-padded Ginv (rows -1,32 = 0)
    __shared__ __align__(16) float s_z[4][3][32];       // [t][q][e]
    __shared__ float s_kern[4][9];
    __shared__ float s_part[4][4];                      // [wave][t]
    __shared__ float s_scale[4];
    __shared__ float s_dtmp[128];

    const float4* Y4 = (const float4*)Yr;
    const float4* A4 = (const float4*)A32;

    float4 yv[4];
    #pragma unroll
    for (int t = 0; t < 4; ++t) yv[t] = Y4[(((b4 << 2) + t) << 8) + tid];

    // stage padded Ginv
    ((float4*)(s_ginvP + 32))[tid] = ((const float4*)Ginv)[tid];
    if (tid < 16) {
        float4 z4 = {0.f, 0.f, 0.f, 0.f};
        if (tid < 8) ((float4*)s_ginvP)[tid] = z4;
        else         ((float4*)(s_ginvP + 33 * 32))[tid - 8] = z4;
    }
    if (tid >= 64 && tid < 192) {
        int e = tid - 64, t = e >> 5, c = e & 31, j = (b4 << 2) + t;
        s_beta4[c][t] = (phase == 0) ? bsrc[(c << 10) + j] : bsrc[j * 32 + c];
    }
    if (tid >= 192 && tid < 228) {
        int e = tid - 192, t = e / 9, r = e % 9, j = (b4 << 2) + t;
        s_kern[t][r] = (phase == 0) ? kb[j * 9 + r] : kb[j * 9 + (r % 3) * 3 + (r / 3)];
    }
    __syncthreads();                                     // B1

    // ---- matvec: r[t] = y[t] - A^T-rows dot beta[t] ----
    auto matvec = [&](float4* r) {
        #pragma unroll
        for (int t = 0; t < 4; ++t) r[t] = yv[t];
        for (int c = 0; c < 32; ++c) {
            float4 bb = *((const float4*)s_beta4[c]);
            float4 a = A4[(c << 8) + tid];
            r[0].x -= a.x * bb.x; r[0].y -= a.y * bb.x; r[0].z -= a.z * bb.x; r[0].w -= a.w * bb.x;
            r[1].x -= a.x * bb.y; r[1].y -= a.y * bb.y; r[1].z -= a.z * bb.y; r[1].w -= a.w * bb.y;
            r[2].x -= a.x * bb.z; r[2].y -= a.y * bb.z; r[2].z -= a.z * bb.z; r[2].w -= a.w * bb.z;
            r[3].x -= a.x * bb.w; r[3].y -= a.y * bb.w; r[3].z -= a.z * bb.w; r[3].w -= a.w * bb.w;
        }
    };

    float4 r[4];
    matvec(r);
    #pragma unroll
    for (int t = 0; t < 4; ++t) ((float4*)s_rp[t])[tid] = r[t];
    __syncthreads();                                     // B2

    // ---- per-wave exact medians -> initial scale ----
    {
        float fv[16]; unsigned kk[16];
        #pragma unroll
        for (int v = 0; v < 16; ++v) fv[v] = s_rp[wv_id][lane + (v << 6)];
        #pragma unroll
        for (int v = 0; v < 16; ++v) kk[v] = f2k(fv[v]);
        float med = wave_median(kk);
        #pragma unroll
        for (int v = 0; v < 16; ++v) kk[v] = f2k(fabsf(fv[v] - med));
        float mad = wave_median(kk);
        if (lane == 0) s_scale[wv_id] = 1.4815f * mad;
    }
    __syncthreads();                                     // B3

    float scale[4];
    #pragma unroll
    for (int t = 0; t < 4; ++t) scale[t] = s_scale[t];

    const float inv_denom = 1.0f / (2.0f * 0.7102f * (1024.0f - 32.0f - 1.0f));
    const float C2 = C_HUB * C_HUB;

    for (int it = 0; it < 3; ++it) {
        matvec(r);

        // r_chi = 0.5*min(u^2, C^2); block sum per task
        #pragma unroll
        for (int t = 0; t < 4; ++t) {
            float s = scale[t];
            float u0 = r[t].x / s, u1 = r[t].y / s, u2 = r[t].z / s, u3 = r[t].w / s;
            float part = 0.5f * (fminf(u0 * u0, C2) + fminf(u1 * u1, C2) +
                                 fminf(u2 * u2, C2) + fminf(u3 * u3, C2));
            float ps = wsum63(part);
            if (lane == 63) s_part[wv_id][t] = ps;
        }
        __syncthreads();                                 // B4

        // scale update + r_pseu -> LDS
        #pragma unroll
        for (int t = 0; t < 4; ++t) {
            float ss = s_part[0][t] + s_part[1][t] + s_part[2][t] + s_part[3][t];
            float s = sqrtf(2.0f * scale[t] * scale[t] * inv_denom * ss);
            scale[t] = s;
            float4 rp;
            rp.x = fminf(fmaxf(r[t].x / s, -C_HUB), C_HUB) * s;
            rp.y = fminf(fmaxf(r[t].y / s, -C_HUB), C_HUB) * s;
            rp.z = fminf(fmaxf(r[t].z / s, -C_HUB), C_HUB) * s;
            rp.w = fminf(fmaxf(r[t].w / s, -C_HUB), C_HUB) * s;
            ((float4*)s_rp[t])[tid] = rp;
        }
        __syncthreads();                                 // B5

        // ---- z[q][e] = sum_j A32[e][j] * rp[j+1-q] (shifted-W form, shifts on A) ----
        #pragma unroll
        for (int half = 0; half < 2; ++half) {
            float a0[4][4], a1[4][4], a2[4][4];
            #pragma unroll
            for (int cc = 0; cc < 4; ++cc)
                #pragma unroll
                for (int t = 0; t < 4; ++t) { a0[cc][t] = 0.f; a1[cc][t] = 0.f; a2[cc][t] = 0.f; }
            float wlast[4] = {0.f, 0.f, 0.f, 0.f};
            float rplast[4] = {0.f, 0.f, 0.f, 0.f};
            #pragma unroll
            for (int kk = 0; kk < 4; ++kk) {
                float4 rp4[4]; float rpl_new[4];
                #pragma unroll
                for (int t = 0; t < 4; ++t) {
                    rp4[t] = ((const float4*)s_rp[t])[(kk << 6) + lane];
                    rpl_new[t] = bcast63(rp4[t].w);
                }
                #pragma unroll
                for (int cc = 0; cc < 4; ++cc) {
                    const int cp = (wv_id << 3) + (half << 2) + cc;
                    float4 w4 = A4[(cp << 8) + (kk << 6) + lane];
                    float wprev = __shfl_up(w4.w, 1, 64);
                    if (lane == 0) wprev = wlast[cc];           // A[e][-1-ish chunk edge]
                    float wnext = __shfl_down(w4.x, 1, 64);
                    if (lane == 63) wnext = 0.f;                // deferred to next chunk
                    float wcomp = (lane == 0) ? w4.x : 0.f;     // deferred-term carrier
                    #pragma unroll
                    for (int t = 0; t < 4; ++t) {
                        float4 rp = rp4[t];
                        a1[cc][t] += w4.x * rp.x + w4.y * rp.y + w4.z * rp.z + w4.w * rp.w;
                        a0[cc][t] += wprev * rp.x + w4.x * rp.y + w4.y * rp.z + w4.z * rp.w;
                        a2[cc][t] += w4.y * rp.x + w4.z * rp.y + w4.w * rp.z + wnext * rp.w
                                   + wcomp * rplast[t];
                    }
                    wlast[cc] = bcast63(w4.w);
                }
                #pragma unroll
                for (int t = 0; t < 4; ++t) rplast[t] = rpl_new[t];
            }
            #pragma unroll
            for (int cc = 0; cc < 4; ++cc) {
                const int cp = (wv_id << 3) + (half << 2) + cc;
                #pragma unroll
                for (int t = 0; t < 4; ++t) {
                    float z0 = wsum63(a0[cc][t]);
                    float z1 = wsum63(a1[cc][t]);
                    float z2 = wsum63(a2[cc][t]);
                    if (lane == 63) {
                        s_z[t][0][cp] = z0; s_z[t][1][cp] = z1; s_z[t][2][cp] = z2;
                    }
                }
            }
        }
        __syncthreads();                                 // B6

        // ---- beta[c][t] += sum_{e,q} (sum_p kern[p][q] G[c+p-1][e]) z[q][e] ----
        {
            int base = tid & 127;
            int t = base >> 5, c = base & 31;
            int e0 = (tid >> 7) << 2;                    // float4-group start: 0 or 4 (of 8)
            float kn[9];
            #pragma unroll
            for (int x = 0; x < 9; ++x) kn[x] = s_kern[t][x];
            const float4* z0p = (const float4*)s_z[t][0];
            const float4* z1p = (const float4*)s_z[t][1];
            const float4* z2p = (const float4*)s_z[t][2];
            const float4* gmp = (const float4*)(s_ginvP + (c << 5));        // row c-1 (padded)
            const float4* gcp = (const float4*)(s_ginvP + ((c + 1) << 5));  // row c
            const float4* gpp = (const float4*)(s_ginvP + ((c + 2) << 5));  // row c+1
            float d = 0.f;
            #pragma unroll
            for (int g = 0; g < 4; ++g) {
                int e4 = e0 + g;
                float4 z0 = z0p[e4], z1 = z1p[e4], z2 = z2p[e4];
                float4 gm = gmp[e4], gc = gcp[e4], gp = gpp[e4];
                d += (kn[0]*gm.x + kn[3]*gc.x + kn[6]*gp.x) * z0.x
                   + (kn[1]*gm.x + kn[4]*gc.x + kn[7]*gp.x) * z1.x
                   + (kn[2]*gm.x + kn[5]*gc.x + kn[8]*gp.x) * z2.x;
                d += (kn[0]*gm.y + kn[3]*gc.y + kn[6]*gp.y) * z0.y
                   + (kn[1]*gm.y + kn[4]*gc.y + kn[7]*gp.y) * z1.y
                   + (kn[2]*gm.y + kn[5]*gc.y + kn[8]*gp.y) * z2.y;
                d += (kn[0]*gm.z + kn[3]*gc.z + kn[6]*gp.z) * z0.z
                   + (kn[1]*gm.z + kn[4]*gc.z + kn[7]*gp.z) * z1.z
                   + (kn[2]*gm.z + kn[5]*gc.z + kn[8]*gp.z) * z2.z;
                d += (kn[0]*gm.w + kn[3]*gc.w + kn[6]*gp.w) * z0.w
                   + (kn[1]*gm.w + kn[4]*gc.w + kn[7]*gp.w) * z1.w
                   + (kn[2]*gm.w + kn[5]*gc.w + kn[8]*gp.w) * z2.w;
            }
            if (tid >= 128) s_dtmp[base] = d;
            __syncthreads();                             // B7
            if (tid < 128) s_beta4[c][t] += d + s_dtmp[base];
        }
        __syncthreads();                                 // B8
    }

    if (tid < 128) {
        int t = tid >> 5, c = tid & 31, j = (b4 << 2) + t;
        float bv = s_beta4[c][t];
        if (phase == 0) {
            vnew[(c << 10) + j] = bv;
            out[c * 2048 + 1024 + j] = bv;
        } else {
            out[c * 2048 + j] = bv;
        }
    }
}

// ---------------------------------------------------------------------------
extern "C" void kernel_launch(void* const* d_in, const int* in_sizes, int n_in,
                              void* d_out, int out_size, void* d_ws, size_t ws_size,
                              hipStream_t stream) {
    const float* X  = (const float*)d_in[0];
    const float* U  = (const float*)d_in[1];
    const float* V  = (const float*)d_in[2];
    const float* CK = (const float*)d_in[3];
    float* out = (float*)d_out;

    float* f     = (float*)d_ws;
    float* XT    = f;                    // 1024*1024
    float* UT    = f + (1 << 20);        // 32*1024
    float* Vn    = UT + 32768;           // 32*1024
    float* Gpart = Vn + 32768;           // 8*1024
    float* Ginv  = Gpart + 8192;         // 1024

    transpose_kernel<<<dim3(32, 33), dim3(32, 8), 0, stream>>>(X, XT, U, UT);

    gram_kernel<<<8, 256, 0, stream>>>(UT, Gpart);
    inv_kernel<<<1, 64, 0, stream>>>(Gpart, Ginv);
    irls_kernel<<<256, 256, 0, stream>>>(XT, UT, Ginv, CK, V, Vn, out, 0);

    gram_kernel<<<8, 256, 0, stream>>>(Vn, Gpart);
    inv_kernel<<<1, 64, 0, stream>>>(Gpart, Ginv);
    irls_kernel<<<256, 256, 0, stream>>>(X, Vn, Ginv, CK + 1023 * 9, U, nullptr, out, 1);
}

// Round 5
// 236.400 us; speedup vs baseline: 2.8792x; 1.1780x over previous
//
#include <hip/hip_runtime.h>
#include <math.h>

#define C_HUB 1.345f

// ---------------- DPP helpers (VALU-pipe cross-lane) ----
template<int CTRL, bool BC>
__device__ __forceinline__ float fdpp(float old_, float src) {
    return __int_as_float(__builtin_amdgcn_update_dpp(
        __float_as_int(old_), __float_as_int(src), CTRL, 0xf, 0xf, BC));
}
// wave64 sum; result valid at lane 63 only
__device__ __forceinline__ float wsum63(float v) {
    v += fdpp<0x111, true>(0.f, v);   // row_shr:1
    v += fdpp<0x112, true>(0.f, v);   // row_shr:2
    v += fdpp<0x114, true>(0.f, v);   // row_shr:4
    v += fdpp<0x118, true>(0.f, v);   // row_shr:8
    v += fdpp<0x142, true>(0.f, v);   // row_bcast:15
    v += fdpp<0x143, true>(0.f, v);   // row_bcast:31
    return v;
}
template<int CTRL>
__device__ __forceinline__ unsigned udpp_keep(unsigned v) {
    return (unsigned)__builtin_amdgcn_update_dpp((int)v, (int)v, CTRL, 0xf, 0xf, false);
}
// wave64 unsigned min; valid at lane 63
__device__ __forceinline__ unsigned wmin63(unsigned v) {
    v = min(v, udpp_keep<0x111>(v));
    v = min(v, udpp_keep<0x112>(v));
    v = min(v, udpp_keep<0x114>(v));
    v = min(v, udpp_keep<0x118>(v));
    v = min(v, udpp_keep<0x142>(v));
    v = min(v, udpp_keep<0x143>(v));
    return v;
}
__device__ __forceinline__ float bcast63(float v) {
    return __int_as_float(__builtin_amdgcn_readlane(__float_as_int(v), 63));
}

// monotone f32 <-> u32 key maps
__device__ __forceinline__ unsigned f2k(float f) {
    unsigned b = __float_as_uint(f);
    return (b & 0x80000000u) ? ~b : (b | 0x80000000u);
}
__device__ __forceinline__ float k2f(unsigned k) {
    return __uint_as_float((k & 0x80000000u) ? (k ^ 0x80000000u) : ~k);
}

// n-th smallest (1-indexed) of 1024 keys (16/lane), wave-synchronous
__device__ __forceinline__ unsigned wave_sel(const unsigned k[16], int n) {
    unsigned hi = 0u;
    for (int b = 31; b >= 0; --b) {
        unsigned pat = hi >> b;
        int cnt = 0;
        #pragma unroll
        for (int v = 0; v < 16; ++v)
            cnt += __popcll(__ballot((k[v] >> b) == pat));
        if (n > cnt) { hi |= (1u << b); n -= cnt; }
    }
    return hi;
}
// exact median (mean of middle two) of the 1024 keys
__device__ __forceinline__ float wave_median(const unsigned k[16]) {
    unsigned k1 = wave_sel(k, 512);
    int cle = 0;
    #pragma unroll
    for (int v = 0; v < 16; ++v) cle += __popcll(__ballot(k[v] <= k1));
    unsigned k2 = k1;
    if (cle < 513) {
        unsigned mg = 0xFFFFFFFFu;
        #pragma unroll
        for (int v = 0; v < 16; ++v) if (k[v] > k1) mg = min(mg, k[v]);
        mg = wmin63(mg);
        k2 = (unsigned)__builtin_amdgcn_readlane((int)mg, 63);
    }
    return 0.5f * (k2f(k1) + k2f(k2));
}

// ---------------------------------------------------------------------------
// Fused transpose: X (1024x1024)->XT plus U (1024x32)->UT (blocks with by==32)
// ---------------------------------------------------------------------------
__global__ void transpose_kernel(const float* __restrict__ X, float* __restrict__ XT,
                                 const float* __restrict__ U, float* __restrict__ UT) {
    if (blockIdx.y == 32) {
        int id = blockIdx.x * 256 + threadIdx.y * 32 + threadIdx.x;  // 0..8191
        #pragma unroll
        for (int s = 0; s < 4; ++s) {
            int e = id + s * 8192;
            int c = e >> 10, m = e & 1023;
            UT[e] = U[m * 32 + c];
        }
        return;
    }
    __shared__ float tile[32][33];
    int bx = blockIdx.x, by = blockIdx.y;
    int x = bx * 32 + threadIdx.x;
    int ybase = by * 32;
    for (int dy = threadIdx.y; dy < 32; dy += 8)
        tile[dy][threadIdx.x] = X[(ybase + dy) * 1024 + x];
    __syncthreads();
    int xo = by * 32 + threadIdx.x;
    int yob = bx * 32;
    for (int dy = threadIdx.y; dy < 32; dy += 8)
        XT[(yob + dy) * 1024 + xo] = tile[threadIdx.x][dy];
}

// ---------------------------------------------------------------------------
// Partial Gram: block b computes AT[:,128b:128b+128] * (same)^T into Gpart[b]
// ---------------------------------------------------------------------------
__global__ __launch_bounds__(256) void gram_kernel(const float* __restrict__ AT,
                                                   float* __restrict__ Gpart) {
    __shared__ float s[32][129];
    const int b = blockIdx.x, tid = threadIdx.x;
    const int k0 = b << 7;
    for (int i = tid; i < 4096; i += 256) {
        int r = i >> 7, c = i & 127;
        s[r][c] = AT[(r << 10) + k0 + c];
    }
    __syncthreads();
    const int c2 = tid & 31, c1b = tid >> 5;
    float acc[4] = {0.f, 0.f, 0.f, 0.f};
    for (int k = 0; k < 128; ++k) {
        float bv = s[c2][k];
        #pragma unroll
        for (int i = 0; i < 4; ++i)
            acc[i] += s[c1b + (i << 3)][k] * bv;
    }
    #pragma unroll
    for (int i = 0; i < 4; ++i)
        Gpart[(b << 10) + ((c1b + (i << 3)) << 5) + c2] = acc[i];
}

// ---------------------------------------------------------------------------
// Sum partials, invert 32x32 SPD Gram via f32 Gauss-Jordan on one wave.
// ---------------------------------------------------------------------------
__global__ __launch_bounds__(64) void inv_kernel(const float* __restrict__ Gpart,
                                                 float* __restrict__ Ginv) {
    const int lane = threadIdx.x;
    float col[32];
    if (lane < 32) {
        #pragma unroll
        for (int r = 0; r < 32; ++r) {
            float a = 0.f;
            #pragma unroll
            for (int b = 0; b < 8; ++b) a += Gpart[(b << 10) + (r << 5) + lane];
            col[r] = a;
        }
    } else {
        #pragma unroll
        for (int r = 0; r < 32; ++r) col[r] = (lane - 32 == r) ? 1.f : 0.f;
    }
    #pragma unroll
    for (int k = 0; k < 32; ++k) {
        float piv = __shfl(col[k], k, 64);
        float pr = 1.0f / piv;
        col[k] *= pr;
        #pragma unroll
        for (int r = 0; r < 32; ++r) {
            if (r == k) continue;
            float f = __shfl(col[r], k, 64);
            col[r] -= f * col[k];
        }
    }
    if (lane >= 32) {
        #pragma unroll
        for (int r = 0; r < 32; ++r)
            Ginv[(r << 5) + (lane - 32)] = col[r];
    }
}

// ---------------------------------------------------------------------------
// IRLS: 2 tasks per block (tasks j = 2*blockIdx.x + t), 256 threads, 512 blocks.
// Thread i owns elements 4i..4i+3. Wave t (t<2) owns task t's medians.
// z[q] = A * shifted-rp; Ginv (symmetric) folded into the beta update.
// Register budget pinned to <=128 VGPR (2 blocks/CU) — spills were R3's killer.
// ---------------------------------------------------------------------------
__global__ __launch_bounds__(256, 2) void irls_kernel(
    const float* __restrict__ Yr, const float* __restrict__ A32,
    const float* __restrict__ Ginv, const float* __restrict__ kb,
    const float* __restrict__ bsrc, float* __restrict__ vnew,
    float* __restrict__ out, int phase)
{
    const int b2 = blockIdx.x;
    const int tid = threadIdx.x;
    const int lane = tid & 63, wv_id = tid >> 6;

    __shared__ __align__(16) float s_rp[2][1024];
    __shared__ __align__(16) float s_beta[32][2];     // [c][t]
    __shared__ float s_g[32][35];                     // s_g[e][1+c] = Ginv[e][c]; cols 0,33 zero
    __shared__ float s_z[2][3][32];                   // [t][q][e]
    __shared__ float s_kern[2][9];
    __shared__ float s_part[4][2];                    // [wave][t]
    __shared__ float s_scale[2];

    const float4* Y4 = (const float4*)Yr;
    const float4* A4 = (const float4*)A32;

    float4 yv[2];
    #pragma unroll
    for (int t = 0; t < 2; ++t) yv[t] = Y4[(((b2 << 1) + t) << 8) + tid];

    // stage Ginv with zero guard columns (symmetric: [e][1+c] indexing == G[c][e])
    for (int i = tid; i < 1024; i += 256) {
        int e = i >> 5, c = i & 31;
        s_g[e][1 + c] = Ginv[i];
    }
    if (tid < 32) s_g[tid][0] = 0.f;
    else if (tid < 64) s_g[tid - 32][33] = 0.f;
    if (tid >= 64 && tid < 128) {
        int e = tid - 64, t = e >> 5, c = e & 31, j = (b2 << 1) + t;
        s_beta[c][t] = (phase == 0) ? bsrc[(c << 10) + j] : bsrc[j * 32 + c];
    }
    if (tid >= 192 && tid < 210) {
        int e = tid - 192, t = e / 9, r = e % 9, j = (b2 << 1) + t;
        s_kern[t][r] = (phase == 0) ? kb[j * 9 + r] : kb[j * 9 + (r % 3) * 3 + (r / 3)];
    }
    __syncthreads();                                     // B1

    // ---- matvec: r[t] = y[t] - A-rows dot beta[t] ----
    auto matvec = [&](float4* r) {
        #pragma unroll
        for (int t = 0; t < 2; ++t) r[t] = yv[t];
        for (int c = 0; c < 32; ++c) {
            float2 bb = *((const float2*)s_beta[c]);
            float4 a = A4[(c << 8) + tid];
            r[0].x -= a.x * bb.x; r[0].y -= a.y * bb.x; r[0].z -= a.z * bb.x; r[0].w -= a.w * bb.x;
            r[1].x -= a.x * bb.y; r[1].y -= a.y * bb.y; r[1].z -= a.z * bb.y; r[1].w -= a.w * bb.y;
        }
    };

    float4 r[2];
    matvec(r);
    #pragma unroll
    for (int t = 0; t < 2; ++t) ((float4*)s_rp[t])[tid] = r[t];
    __syncthreads();                                     // B2

    // ---- per-wave exact medians -> initial scale (waves 0,1 only) ----
    if (wv_id < 2) {
        float fv[16]; unsigned kk[16];
        #pragma unroll
        for (int v = 0; v < 16; ++v) fv[v] = s_rp[wv_id][lane + (v << 6)];
        #pragma unroll
        for (int v = 0; v < 16; ++v) kk[v] = f2k(fv[v]);
        float med = wave_median(kk);
        #pragma unroll
        for (int v = 0; v < 16; ++v) kk[v] = f2k(fabsf(fv[v] - med));
        float mad = wave_median(kk);
        if (lane == 0) s_scale[wv_id] = 1.4815f * mad;
    }
    __syncthreads();                                     // B3

    float scale[2];
    #pragma unroll
    for (int t = 0; t < 2; ++t) scale[t] = s_scale[t];

    const float inv_denom = 1.0f / (2.0f * 0.7102f * (1024.0f - 32.0f - 1.0f));
    const float C2 = C_HUB * C_HUB;

    for (int it = 0; it < 3; ++it) {
        matvec(r);

        // r_chi = 0.5*min(u^2, C^2); block sum per task
        #pragma unroll
        for (int t = 0; t < 2; ++t) {
            float s = scale[t];
            float u0 = r[t].x / s, u1 = r[t].y / s, u2 = r[t].z / s, u3 = r[t].w / s;
            float part = 0.5f * (fminf(u0 * u0, C2) + fminf(u1 * u1, C2) +
                                 fminf(u2 * u2, C2) + fminf(u3 * u3, C2));
            float ps = wsum63(part);
            if (lane == 63) s_part[wv_id][t] = ps;
        }
        __syncthreads();                                 // B4

        // scale update + r_pseu -> LDS
        #pragma unroll
        for (int t = 0; t < 2; ++t) {
            float ss = s_part[0][t] + s_part[1][t] + s_part[2][t] + s_part[3][t];
            float s = sqrtf(2.0f * scale[t] * scale[t] * inv_denom * ss);
            scale[t] = s;
            float4 rp;
            rp.x = fminf(fmaxf(r[t].x / s, -C_HUB), C_HUB) * s;
            rp.y = fminf(fmaxf(r[t].y / s, -C_HUB), C_HUB) * s;
            rp.z = fminf(fmaxf(r[t].z / s, -C_HUB), C_HUB) * s;
            rp.w = fminf(fmaxf(r[t].w / s, -C_HUB), C_HUB) * s;
            ((float4*)s_rp[t])[tid] = rp;
        }
        __syncthreads();                                 // B5

        // ---- z[q][e] = sum_j A32[e][j] * rp[j+1-q] (shifts applied to A) ----
        #pragma unroll 1
        for (int half = 0; half < 2; ++half) {
            float a0[4][2], a1[4][2], a2[4][2];
            #pragma unroll
            for (int cc = 0; cc < 4; ++cc)
                #pragma unroll
                for (int t = 0; t < 2; ++t) { a0[cc][t] = 0.f; a1[cc][t] = 0.f; a2[cc][t] = 0.f; }
            float wlast[4] = {0.f, 0.f, 0.f, 0.f};
            float rplast[2] = {0.f, 0.f};
            #pragma unroll
            for (int kk = 0; kk < 4; ++kk) {
                float4 rp4[2]; float rpl_new[2];
                #pragma unroll
                for (int t = 0; t < 2; ++t) {
                    rp4[t] = ((const float4*)s_rp[t])[(kk << 6) + lane];
                    rpl_new[t] = bcast63(rp4[t].w);
                }
                #pragma unroll
                for (int cc = 0; cc < 4; ++cc) {
                    const int cp = (wv_id << 3) + (half << 2) + cc;
                    float4 w4 = A4[(cp << 8) + (kk << 6) + lane];
                    float wprev = __shfl_up(w4.w, 1, 64);
                    if (lane == 0) wprev = wlast[cc];
                    float wnext = __shfl_down(w4.x, 1, 64);
                    if (lane == 63) wnext = 0.f;
                    float wcomp = (lane == 0) ? w4.x : 0.f;   // deferred chunk-edge term
                    #pragma unroll
                    for (int t = 0; t < 2; ++t) {
                        float4 rp = rp4[t];
                        a1[cc][t] += w4.x * rp.x + w4.y * rp.y + w4.z * rp.z + w4.w * rp.w;
                        a0[cc][t] += wprev * rp.x + w4.x * rp.y + w4.y * rp.z + w4.z * rp.w;
                        a2[cc][t] += w4.y * rp.x + w4.z * rp.y + w4.w * rp.z + wnext * rp.w
                                   + wcomp * rplast[t];
                    }
                    wlast[cc] = bcast63(w4.w);
                }
                #pragma unroll
                for (int t = 0; t < 2; ++t) rplast[t] = rpl_new[t];
            }
            #pragma unroll
            for (int cc = 0; cc < 4; ++cc) {
                const int cp = (wv_id << 3) + (half << 2) + cc;
                #pragma unroll
                for (int t = 0; t < 2; ++t) {
                    float z0 = wsum63(a0[cc][t]);
                    float z1 = wsum63(a1[cc][t]);
                    float z2 = wsum63(a2[cc][t]);
                    if (lane == 63) {
                        s_z[t][0][cp] = z0; s_z[t][1][cp] = z1; s_z[t][2][cp] = z2;
                    }
                }
            }
        }
        __syncthreads();                                 // B6

        // ---- beta[c][t] += sum_e sum_q (sum_p kern[p][q] G[c+p-1][e]) z[q][e]
        //      G[x][e] read via symmetry as s_g[e][1+x]; guard cols handle x=-1,32.
        if (tid < 64) {
            int t = tid >> 5, c = tid & 31;
            float kn[9];
            #pragma unroll
            for (int x = 0; x < 9; ++x) kn[x] = s_kern[t][x];
            float d = 0.f;
            #pragma unroll 4
            for (int e = 0; e < 32; ++e) {
                float gm = s_g[e][c];       // G[c-1][e]
                float gc = s_g[e][c + 1];   // G[c  ][e]
                float gp = s_g[e][c + 2];   // G[c+1][e]
                float z0 = s_z[t][0][e], z1 = s_z[t][1][e], z2 = s_z[t][2][e];
                d += (kn[0] * gm + kn[3] * gc + kn[6] * gp) * z0
                   + (kn[1] * gm + kn[4] * gc + kn[7] * gp) * z1
                   + (kn[2] * gm + kn[5] * gc + kn[8] * gp) * z2;
            }
            s_beta[c][t] += d;
        }
        __syncthreads();                                 // B7
    }

    if (tid < 64) {
        int t = tid >> 5, c = tid & 31, j = (b2 << 1) + t;
        float bv = s_beta[c][t];
        if (phase == 0) {
            vnew[(c << 10) + j] = bv;
            out[c * 2048 + 1024 + j] = bv;
        } else {
            out[c * 2048 + j] = bv;
        }
    }
}

// ---------------------------------------------------------------------------
extern "C" void kernel_launch(void* const* d_in, const int* in_sizes, int n_in,
                              void* d_out, int out_size, void* d_ws, size_t ws_size,
                              hipStream_t stream) {
    const float* X  = (const float*)d_in[0];
    const float* U  = (const float*)d_in[1];
    const float* V  = (const float*)d_in[2];
    const float* CK = (const float*)d_in[3];
    float* out = (float*)d_out;

    float* f     = (float*)d_ws;
    float* XT    = f;                    // 1024*1024
    float* UT    = f + (1 << 20);        // 32*1024
    float* Vn    = UT + 32768;           // 32*1024
    float* Gpart = Vn + 32768;           // 8*1024
    float* Ginv  = Gpart + 8192;         // 1024

    transpose_kernel<<<dim3(32, 33), dim3(32, 8), 0, stream>>>(X, XT, U, UT);

    gram_kernel<<<8, 256, 0, stream>>>(UT, Gpart);
    inv_kernel<<<1, 64, 0, stream>>>(Gpart, Ginv);
    irls_kernel<<<512, 256, 0, stream>>>(XT, UT, Ginv, CK, V, Vn, out, 0);

    gram_kernel<<<8, 256, 0, stream>>>(Vn, Gpart);
    inv_kernel<<<1, 64, 0, stream>>>(Gpart, Ginv);
    irls_kernel<<<512, 256, 0, stream>>>(X, Vn, Ginv, CK + 1023 * 9, U, nullptr, out, 1);
}